// Round 9
// baseline (242.324 us; speedup 1.0000x reference)
//
#include <hip/hip_runtime.h>
#include <stdint.h>

// SelfAttentionBlock: B=4, C=256, H=W=64 (N=4096), CQK=32.
//   cvt : W fp32->f16 (Wh) + x -> f16 transposed xh[b][n][c]
//   proj: register MFMA GEMM -> Qt[n][32]*log2e, Kt[n][32],
//         Vp = V pre-packed in PV B-fragment order [b][jblk][ct][lane][8]
//   attn: flash attention, 1024 thr = 4 j-groups x 4 waves = 4 waves/SIMD
//         (amdgpu_waves_per_eu(4,4) pins the VGPR budget at 128 - no r7 spills).
//         Per-wave structure identical to round 8 (96 VGPR): V direct from L2
//         via coalesced Vp frags, K global->reg prefetch, swapped QK^T,
//         lane-owns-row softmax, defer-max, log2 domain, P double-buffered in
//         LDS, ONE lgkm-only barrier per 64-j step (16 steps/group).
//         4-way flash combine in epilogue.

#define NB 4
#define CD 256
#define ND 4096
#define CQ 32
#define LOG2E 1.4426950408889634f

typedef __attribute__((ext_vector_type(4))) float f32x4;
typedef __attribute__((ext_vector_type(8))) _Float16 f16x8;
typedef __attribute__((ext_vector_type(4))) unsigned short u16x4;
typedef __attribute__((ext_vector_type(8))) unsigned short u16x8;
typedef __attribute__((ext_vector_type(2))) unsigned int u32x2;
typedef __attribute__((ext_vector_type(4))) int i32x4;

static __device__ __forceinline__ unsigned short f2h(float f) {
    union { _Float16 h; unsigned short u; } cv; cv.h = (_Float16)f; return cv.u;
}
static __device__ __forceinline__ float fexp2(float xv) {
    float r; asm("v_exp_f32 %0, %1" : "=v"(r) : "v"(xv)); return r;
}

#define BARRIER() asm volatile("s_waitcnt lgkmcnt(0)\n\ts_barrier" ::: "memory")

// ---------------- fused cvt: W fp32->f16 and x -> xh[b][n][c] f16 ----------------
__global__ __launch_bounds__(256) void cvt_kernel(
    const float* __restrict__ x,
    const float* __restrict__ wq, const float* __restrict__ wk,
    const float* __restrict__ wv,
    unsigned short* __restrict__ xh, unsigned short* __restrict__ Wh)
{
    __shared__ unsigned short xt[64 * 72];
    if (blockIdx.x >= 1024) {   // wcvt (80 blocks)
        const int idx = (blockIdx.x - 1024) * 256 + threadIdx.x;
        const int m = idx >> 6, kq = (idx & 63) << 2;
        const float* src = (m < 32) ? (wq + (size_t)m * CD + kq)
                         : (m < 64) ? (wk + (size_t)(m - 32) * CD + kq)
                                    : (wv + (size_t)(m - 64) * CD + kq);
        const f32x4 v = *reinterpret_cast<const f32x4*>(src);
        u16x4 h;
#pragma unroll
        for (int u = 0; u < 4; ++u) h[u] = f2h(v[u]);
        *reinterpret_cast<u16x4*>(Wh + (size_t)m * CD + kq) = h;
        return;
    }
    const int t  = threadIdx.x;
    const int nt = blockIdx.x & 63, ct = (blockIdx.x >> 6) & 3, b = blockIdx.x >> 8;
    const int n0 = nt << 6, c0 = ct << 6;

    const float* xb = x + ((size_t)(b * CD + c0)) * ND + n0;
#pragma unroll
    for (int s = t; s < 1024; s += 256) {
        const int c = s >> 4, nq = (s & 15) << 2;
        const f32x4 v = *reinterpret_cast<const f32x4*>(xb + (size_t)c * ND + nq);
        u16x4 h;
#pragma unroll
        for (int u = 0; u < 4; ++u) h[u] = f2h(v[u]);
        *reinterpret_cast<u16x4*>(&xt[c * 72 + nq]) = h;
    }
    __syncthreads();

    const int n = t >> 2, cb = (t & 3) << 4;
    u16x8 o0, o1;
#pragma unroll
    for (int u = 0; u < 8; ++u) o0[u] = xt[(cb + u) * 72 + n];
#pragma unroll
    for (int u = 0; u < 8; ++u) o1[u] = xt[(cb + 8 + u) * 72 + n];
    unsigned short* dst = xh + ((size_t)(b * ND + n0 + n)) * CD + c0 + cb;
    *reinterpret_cast<u16x8*>(dst)     = o0;
    *reinterpret_cast<u16x8*>(dst + 8) = o1;
}

// ---------------- projection: register MFMA GEMM ----------------
// wave 0: Q,K rows (D[c][n]); waves 1-4: V rows with swapped operands
// (D[n][c]) so each lane's 4 acc values are consecutive n -> one u16x4
// store into the Vp packed-fragment layout.
__global__ __launch_bounds__(320) void proj_kernel(
    const unsigned short* __restrict__ Wh, const unsigned short* __restrict__ xh,
    const float* __restrict__ bq, const float* __restrict__ bk,
    const float* __restrict__ bv,
    unsigned short* __restrict__ Qt, unsigned short* __restrict__ Kt,
    unsigned short* __restrict__ Vp)
{
    const int tid = threadIdx.x;
    const int lane = tid & 63;
    const int w = __builtin_amdgcn_readfirstlane(tid >> 6);
    const int m16 = lane & 15, g4 = lane >> 4;
    const int b = blockIdx.x >> 6, n0 = (blockIdx.x & 63) << 6;

    f32x4 acc[4][4];
#pragma unroll
    for (int a = 0; a < 4; ++a)
#pragma unroll
        for (int c = 0; c < 4; ++c) acc[a][c] = (f32x4){0.f, 0.f, 0.f, 0.f};

    const unsigned short* Wrow = Wh + (size_t)(w * 64 + m16) * CD;
    const unsigned short* Xrow = xh + ((size_t)(b * ND + n0 + m16)) * CD;

#pragma unroll
    for (int ks = 0; ks < 8; ++ks) {
        const int ko = ks * 32 + g4 * 8;
        f16x8 af[4], bf[4];
#pragma unroll
        for (int ms = 0; ms < 4; ++ms)
            af[ms] = *reinterpret_cast<const f16x8*>(Wrow + (size_t)ms * 16 * CD + ko);
#pragma unroll
        for (int ns = 0; ns < 4; ++ns)
            bf[ns] = *reinterpret_cast<const f16x8*>(Xrow + (size_t)ns * 16 * CD + ko);
        if (w == 0) {
#pragma unroll
            for (int ms = 0; ms < 4; ++ms)
#pragma unroll
                for (int ns = 0; ns < 4; ++ns)
                    acc[ms][ns] = __builtin_amdgcn_mfma_f32_16x16x32_f16(
                        af[ms], bf[ns], acc[ms][ns], 0, 0, 0);
        } else {
#pragma unroll
            for (int ms = 0; ms < 4; ++ms)
#pragma unroll
                for (int ns = 0; ns < 4; ++ns)
                    acc[ms][ns] = __builtin_amdgcn_mfma_f32_16x16x32_f16(
                        bf[ns], af[ms], acc[ms][ns], 0, 0, 0);
        }
    }

    if (w == 0) {   // Q (ms 0,1) + K (ms 2,3)
#pragma unroll
        for (int ms = 0; ms < 4; ++ms) {
            const int seg = ms * 16;
            const int mb  = seg + g4 * 4;
            const f32x4 bias = (seg < 32) ? *reinterpret_cast<const f32x4*>(bq + mb)
                                          : *reinterpret_cast<const f32x4*>(bk + (mb - 32));
#pragma unroll
            for (int ns = 0; ns < 4; ++ns) {
                const int n = n0 + ns * 16 + m16;
                u16x4 h;
                if (seg < 32) {
#pragma unroll
                    for (int r = 0; r < 4; ++r)
                        h[r] = f2h(fmaxf(acc[ms][ns][r] + bias[r], 0.f) * LOG2E);
                    *reinterpret_cast<u16x4*>(Qt + ((size_t)(b * ND + n)) * CQ + mb) = h;
                } else {
#pragma unroll
                    for (int r = 0; r < 4; ++r)
                        h[r] = f2h(fmaxf(acc[ms][ns][r] + bias[r], 0.f));
                    *reinterpret_cast<u16x4*>(Kt + ((size_t)(b * ND + n)) * CQ + (mb - 32)) = h;
                }
            }
        }
    } else {        // V: D[n][c], rows n = g4*4+r, cols c = m16
        const int cbase = (w - 1) * 64;
#pragma unroll
        for (int ms = 0; ms < 4; ++ms) {
            const int c = cbase + ms * 16 + m16;
            const float bval = bv[c];
#pragma unroll
            for (int ns = 0; ns < 4; ++ns) {
                const int n = n0 + ns * 16 + g4 * 4;
                u16x4 h;
#pragma unroll
                for (int r = 0; r < 4; ++r)
                    h[r] = f2h(fmaxf(acc[ms][ns][r] + bval, 0.f));
                unsigned short* dst = Vp
                    + ((size_t)((b * 128 + (n >> 5)) * 16 + (c >> 4))) * 512
                    + ((((n >> 3) & 3) * 16 + (c & 15)) * 8) + (n & 7);
                *reinterpret_cast<u16x4*>(dst) = h;
            }
        }
    }
}

// ---------------- flash attention: 16 waves = 4 j-groups x 4 waves ----------------
// grid: NB*64 blocks (b, 64-row i-strip), 1024 threads, 4 waves/SIMD pinned.
// Group g owns j in [g*1024, +1024), 16 steps of 64 j. Per step per wave:
// QK^T (swapped) on 16-i strip -> softmax -> P->LDS -> BARRIER -> rescale -> PV
// on 64-c slice with V frags direct from global/L2. One barrier per step.
__global__ __launch_bounds__(1024) __attribute__((amdgpu_waves_per_eu(4, 4)))
void attn_kernel(
    const unsigned short* __restrict__ Qt, const unsigned short* __restrict__ Kt,
    const unsigned short* __restrict__ Vp, const float* __restrict__ x,
    const float* __restrict__ gamma, float* __restrict__ out)
{
    // 0..65535      p_lds   [4 groups][2 buf][64 i][128 B]  (f16, XOR-swizzled)
    // 65536..67583  scales  [4][2][64] f32
    // 67584..67711  flags   [4][2][4]  i32
    // epilogue: Ocomb [64][260] f32 @0 (aliases loop LDS); mfin/lfin/wfac above
    __shared__ __align__(16) unsigned char smem[70784];
    float* scales = reinterpret_cast<float*>(smem + 65536);
    int*   flags  = reinterpret_cast<int*>(smem + 67584);
    float* Ocomb  = reinterpret_cast<float*>(smem);
    float* mfin   = reinterpret_cast<float*>(smem + 67712);  // [4][64]
    float* lfin   = reinterpret_cast<float*>(smem + 68736);  // [4][64]
    float* wfac   = reinterpret_cast<float*>(smem + 69760);  // [4][64]

    const int tid  = threadIdx.x;
    const int lane = tid & 63;
    const int w16  = __builtin_amdgcn_readfirstlane(tid >> 6);
    const int g    = w16 >> 2;      // j-group 0..3
    const int ws   = w16 & 3;       // i-strip (QK) / c-slice (PV)
    const int m16  = lane & 15;
    const int g4   = lane >> 4;
    const int wg   = (blockIdx.x & 7) * 32 + (blockIdx.x >> 3);  // XCD swizzle
    const int b    = wg >> 6;
    const int i0   = (wg & 63) << 6;

    // Q as B-operand: col=i=ws*16+m16, k=g4*8+u
    const f16x8 qfrag = *reinterpret_cast<const f16x8*>(
        Qt + ((size_t)(b * ND + i0 + ws * 16 + m16)) * CQ + g4 * 8);
    // K as A-operand from global: row j=m16 (+16*jt), k=g4*8+u  (1KB/wave, coalesced)
    const unsigned short* kb = Kt + ((size_t)(b * ND + m16)) * CQ + g4 * 8;
    // V B-frags, packed layout: 16B/lane, 1KB/wave contiguous per frag
    const unsigned short* vpc =
        Vp + ((size_t)(b * 128 * 16 + ws * 4)) * 512 + lane * 8;

    f32x4 oacc[4][4];
#pragma unroll
    for (int a = 0; a < 4; ++a)
#pragma unroll
        for (int c = 0; c < 4; ++c) oacc[a][c] = (f32x4){0.f, 0.f, 0.f, 0.f};
    float mrow = -1e30f, lrow = 0.f;
    const f32x4 zero4 = {0.f, 0.f, 0.f, 0.f};

    const int jbase = g * 1024;
    const int irow  = ws * 16 + m16;
    const int iswz  = (m16 & 7) << 4;     // == (irow&7)<<4

    auto LOADK = [&](f16x8 (&kr)[4], int j) {
#pragma unroll
        for (int t = 0; t < 4; ++t)
            kr[t] = *reinterpret_cast<const f16x8*>(kb + (size_t)(j + t * 16) * CQ);
    };

    auto STEP = [&](int k, f16x8 (&kc)[4], f16x8 (&kn)[4]) {
        const int j0  = jbase + k * 64;
        const int par = k & 1;
        unsigned char* pb = smem + g * 16384 + par * 8192;

        // issue V frag loads now; consumed after the barrier (latency hidden)
        const int jblk0 = j0 >> 5;
        f16x8 vf[2][4];
#pragma unroll
        for (int jh = 0; jh < 2; ++jh)
#pragma unroll
            for (int cs = 0; cs < 4; ++cs)
                vf[jh][cs] = *reinterpret_cast<const f16x8*>(
                    vpc + (size_t)((jblk0 + jh) * 16 + cs) * 512);
        // prefetch next step's K
        const int jn = (k < 15) ? (j0 + 64) : jbase;
        LOADK(kn, jn);

        // ---- QK^T swapped: D[j][i], col=i=irow, lane holds 16 j values ----
        f32x4 s[4];
#pragma unroll
        for (int t = 0; t < 4; ++t)
            s[t] = __builtin_amdgcn_mfma_f32_16x16x32_f16(kc[t], qfrag, zero4, 0, 0, 0);

        // ---- softmax (log2 domain, defer-max) ----
        float pm = s[0][0];
#pragma unroll
        for (int t = 0; t < 4; ++t)
#pragma unroll
            for (int r = 0; r < 4; ++r) pm = fmaxf(pm, s[t][r]);
        pm = fmaxf(pm, __shfl_xor(pm, 16));
        pm = fmaxf(pm, __shfl_xor(pm, 32));
        float sc = 1.0f;
        int myresc = 0;
        if (__ballot(pm <= mrow + 8.0f) != ~0ull) {
            const float mnew = fmaxf(mrow, pm);
            sc = fexp2(mrow - mnew);
            mrow = mnew;
            myresc = 1;
        }
        float rs = 0.f;
#pragma unroll
        for (int t = 0; t < 4; ++t)
#pragma unroll
            for (int r = 0; r < 4; ++r) { s[t][r] = fexp2(s[t][r] - mrow); rs += s[t][r]; }
        rs += __shfl_xor(rs, 16);
        rs += __shfl_xor(rs, 32);
        lrow = lrow * sc + rs;

        // ---- P -> LDS (4x ds_write_b64, swizzled) + scale + flag ----
#pragma unroll
        for (int t = 0; t < 4; ++t) {
            u32x2 pw;
            pw[0] = __builtin_bit_cast(unsigned int,
                        __builtin_amdgcn_cvt_pkrtz(s[t][0], s[t][1]));
            pw[1] = __builtin_bit_cast(unsigned int,
                        __builtin_amdgcn_cvt_pkrtz(s[t][2], s[t][3]));
            const int lo = (irow * 128 + t * 32 + g4 * 8) ^ iswz;
            *reinterpret_cast<u32x2*>(pb + lo) = pw;
        }
        if (g4 == 0)   scales[(g * 2 + par) * 64 + irow] = sc;
        if (lane == 0) flags[(g * 2 + par) * 4 + ws] = myresc;

        BARRIER();   // lgkm-only: P/scale/flag visible; V/K loads stay in flight

        // ---- rescale oacc if any row of the group rescaled ----
        const i32x4 fl = *reinterpret_cast<const i32x4*>(flags + (g * 2 + par) * 4);
        const int anyresc = __builtin_amdgcn_readfirstlane(fl[0] | fl[1] | fl[2] | fl[3]);
        if (anyresc) {
#pragma unroll
            for (int is = 0; is < 4; ++is) {
                const f32x4 sr = *reinterpret_cast<const f32x4*>(
                    scales + (g * 2 + par) * 64 + is * 16 + g4 * 4);
#pragma unroll
                for (int r = 0; r < 4; ++r)
#pragma unroll
                    for (int cs = 0; cs < 4; ++cs) oacc[is][cs][r] *= sr[r];
            }
        }

        // ---- PV: P A-frags from LDS, V B-frags from registers (global) ----
        __builtin_amdgcn_s_setprio(1);
#pragma unroll
        for (int jh = 0; jh < 2; ++jh) {
#pragma unroll
            for (int is = 0; is < 4; ++is) {
                const int lo = ((is * 16 + m16) * 128 + jh * 64 + g4 * 16) ^ iswz;
                const f16x8 pf = *reinterpret_cast<const f16x8*>(pb + lo);
#pragma unroll
                for (int cs = 0; cs < 4; ++cs)
                    oacc[is][cs] = __builtin_amdgcn_mfma_f32_16x16x32_f16(
                        pf, vf[jh][cs], oacc[is][cs], 0, 0, 0);
            }
        }
        __builtin_amdgcn_s_setprio(0);
    };

    f16x8 kA[4], kB[4];
    LOADK(kA, jbase);

#pragma unroll 1
    for (int k2 = 0; k2 < 8; ++k2) {
        STEP(2 * k2,     kA, kB);
        STEP(2 * k2 + 1, kB, kA);
    }

    // ---- epilogue: 4-way flash combine over j-groups ----
    if (g4 == 0) { mfin[g * 64 + irow] = mrow; lfin[g * 64 + irow] = lrow; }
    __syncthreads();

    if (tid < 256) {
        const int gg = tid >> 6, i = tid & 63;
        const float m0 = mfin[i], m1 = mfin[64 + i], m2 = mfin[128 + i], m3 = mfin[192 + i];
        const float M  = fmaxf(fmaxf(m0, m1), fmaxf(m2, m3));
        const float e0 = fexp2(m0 - M), e1 = fexp2(m1 - M),
                    e2 = fexp2(m2 - M), e3 = fexp2(m3 - M);
        const float den = lfin[i] * e0 + lfin[64 + i] * e1 +
                          lfin[128 + i] * e2 + lfin[192 + i] * e3;
        const float eg = (gg == 0) ? e0 : (gg == 1) ? e1 : (gg == 2) ? e2 : e3;
        wfac[gg * 64 + i] = eg / den;
    }
    __syncthreads();   // loop LDS dead; Ocomb aliases it from here

#pragma unroll
    for (int gg = 0; gg < 4; ++gg) {
        if (g == gg) {
#pragma unroll
            for (int is = 0; is < 4; ++is) {
                const f32x4 f = *reinterpret_cast<const f32x4*>(
                    wfac + g * 64 + is * 16 + g4 * 4);
#pragma unroll
                for (int cs = 0; cs < 4; ++cs)
#pragma unroll
                    for (int r = 0; r < 4; ++r) {
                        const int i = is * 16 + g4 * 4 + r;
                        const int c = ws * 64 + cs * 16 + m16;
                        if (gg == 0) Ocomb[i * 260 + c]  = oacc[is][cs][r] * f[r];
                        else         Ocomb[i * 260 + c] += oacc[is][cs][r] * f[r];
                    }
            }
        }
        __syncthreads();
    }

    const float gm = gamma[0];
#pragma unroll
    for (int pass = 0; pass < 4; ++pass) {
        const int q  = tid + pass * 1024;
        const int c  = q >> 4;
        const int ib = (q & 15) * 4;
        f32x4 o;
#pragma unroll
        for (int u = 0; u < 4; ++u) o[u] = Ocomb[(ib + u) * 260 + c];
        const size_t idx = ((size_t)(b * CD + c)) * ND + i0 + ib;
        const f32x4 xv = *reinterpret_cast<const f32x4*>(x + idx);
        f32x4 res;
#pragma unroll
        for (int u = 0; u < 4; ++u) res[u] = gm * o[u] + xv[u];
        *reinterpret_cast<f32x4*>(out + idx) = res;
    }
}

extern "C" void kernel_launch(void* const* d_in, const int* in_sizes, int n_in,
                              void* d_out, int out_size, void* d_ws, size_t ws_size,
                              hipStream_t stream) {
    const float* x     = (const float*)d_in[0];
    const float* wq    = (const float*)d_in[1];
    const float* bq    = (const float*)d_in[2];
    const float* wk    = (const float*)d_in[3];
    const float* bk    = (const float*)d_in[4];
    const float* wv    = (const float*)d_in[5];
    const float* bv    = (const float*)d_in[6];
    const float* gamma = (const float*)d_in[7];

    unsigned short* Qt = (unsigned short*)d_ws;               // 1MB (scaled by log2e)
    unsigned short* Kt = Qt + (size_t)NB * ND * CQ;           // 1MB
    unsigned short* Vp = Kt + (size_t)NB * ND * CQ;           // 8MB packed frags
    unsigned short* Wh = Vp + (size_t)NB * CD * ND;           // 160KB
    unsigned short* xh = Wh + (size_t)320 * CD;               // 8MB
    float* out = (float*)d_out;

    cvt_kernel<<<dim3(1104),     dim3(256),  0, stream>>>(x, wq, wk, wv, xh, Wh);
    proj_kernel<<<dim3(NB * 64), dim3(320),  0, stream>>>(Wh, xh, bq, bk, bv, Qt, Kt, Vp);
    attn_kernel<<<dim3(NB * 64), dim3(1024), 0, stream>>>(Qt, Kt, Vp, x, gamma, out);
}

// Round 10
// 94.652 us; speedup vs baseline: 2.5602x; 2.5602x over previous
//
#include <hip/hip_runtime.h>
#include <stdint.h>

// SelfAttentionBlock: B=4, C=256, H=W=64 (N=4096), CQK=32.
//   cvt : W fp32->f16 (Wh) + x -> f16 transposed xh[b][n][c]
//   proj: register MFMA GEMM -> Qt[n][32]*log2e, Kt[n][32],
//         Vp = V pre-packed in PV B-fragment order [b][jblk][ct][lane][8]
//   attn: flash attention, 512 thr = 2 j-groups x 4 waves (r8 topology, 96->~2xx VGPR).
//         128-j steps (16 barriers total). NO cross-lane shuffles in the common
//         path: defer-max via per-lane local max + ballot; row-sum kept as
//         per-lane partial l reduced once in the epilogue. V direct from L2
//         via coalesced Vp frags; K global->reg prefetch; P double-buffered in
//         LDS (256B rows, XOR swizzle); ONE lgkm-only barrier per step.

#define NB 4
#define CD 256
#define ND 4096
#define CQ 32
#define LOG2E 1.4426950408889634f

typedef __attribute__((ext_vector_type(4))) float f32x4;
typedef __attribute__((ext_vector_type(8))) _Float16 f16x8;
typedef __attribute__((ext_vector_type(4))) unsigned short u16x4;
typedef __attribute__((ext_vector_type(8))) unsigned short u16x8;
typedef __attribute__((ext_vector_type(2))) unsigned int u32x2;
typedef __attribute__((ext_vector_type(4))) int i32x4;

static __device__ __forceinline__ unsigned short f2h(float f) {
    union { _Float16 h; unsigned short u; } cv; cv.h = (_Float16)f; return cv.u;
}
static __device__ __forceinline__ float fexp2(float xv) {
    float r; asm("v_exp_f32 %0, %1" : "=v"(r) : "v"(xv)); return r;
}

#define BARRIER() asm volatile("s_waitcnt lgkmcnt(0)\n\ts_barrier" ::: "memory")

// ---------------- fused cvt: W fp32->f16 and x -> xh[b][n][c] f16 ----------------
__global__ __launch_bounds__(256) void cvt_kernel(
    const float* __restrict__ x,
    const float* __restrict__ wq, const float* __restrict__ wk,
    const float* __restrict__ wv,
    unsigned short* __restrict__ xh, unsigned short* __restrict__ Wh)
{
    __shared__ unsigned short xt[64 * 72];
    if (blockIdx.x >= 1024) {   // wcvt (80 blocks)
        const int idx = (blockIdx.x - 1024) * 256 + threadIdx.x;
        const int m = idx >> 6, kq = (idx & 63) << 2;
        const float* src = (m < 32) ? (wq + (size_t)m * CD + kq)
                         : (m < 64) ? (wk + (size_t)(m - 32) * CD + kq)
                                    : (wv + (size_t)(m - 64) * CD + kq);
        const f32x4 v = *reinterpret_cast<const f32x4*>(src);
        u16x4 h;
#pragma unroll
        for (int u = 0; u < 4; ++u) h[u] = f2h(v[u]);
        *reinterpret_cast<u16x4*>(Wh + (size_t)m * CD + kq) = h;
        return;
    }
    const int t  = threadIdx.x;
    const int nt = blockIdx.x & 63, ct = (blockIdx.x >> 6) & 3, b = blockIdx.x >> 8;
    const int n0 = nt << 6, c0 = ct << 6;

    const float* xb = x + ((size_t)(b * CD + c0)) * ND + n0;
#pragma unroll
    for (int s = t; s < 1024; s += 256) {
        const int c = s >> 4, nq = (s & 15) << 2;
        const f32x4 v = *reinterpret_cast<const f32x4*>(xb + (size_t)c * ND + nq);
        u16x4 h;
#pragma unroll
        for (int u = 0; u < 4; ++u) h[u] = f2h(v[u]);
        *reinterpret_cast<u16x4*>(&xt[c * 72 + nq]) = h;
    }
    __syncthreads();

    const int n = t >> 2, cb = (t & 3) << 4;
    u16x8 o0, o1;
#pragma unroll
    for (int u = 0; u < 8; ++u) o0[u] = xt[(cb + u) * 72 + n];
#pragma unroll
    for (int u = 0; u < 8; ++u) o1[u] = xt[(cb + 8 + u) * 72 + n];
    unsigned short* dst = xh + ((size_t)(b * ND + n0 + n)) * CD + c0 + cb;
    *reinterpret_cast<u16x8*>(dst)     = o0;
    *reinterpret_cast<u16x8*>(dst + 8) = o1;
}

// ---------------- projection: register MFMA GEMM ----------------
// wave 0: Q,K rows (D[c][n]); waves 1-4: V rows with swapped operands
// (D[n][c]) so each lane's 4 acc values are consecutive n -> one u16x4
// store into the Vp packed-fragment layout.
__global__ __launch_bounds__(320) void proj_kernel(
    const unsigned short* __restrict__ Wh, const unsigned short* __restrict__ xh,
    const float* __restrict__ bq, const float* __restrict__ bk,
    const float* __restrict__ bv,
    unsigned short* __restrict__ Qt, unsigned short* __restrict__ Kt,
    unsigned short* __restrict__ Vp)
{
    const int tid = threadIdx.x;
    const int lane = tid & 63;
    const int w = __builtin_amdgcn_readfirstlane(tid >> 6);
    const int m16 = lane & 15, g4 = lane >> 4;
    const int b = blockIdx.x >> 6, n0 = (blockIdx.x & 63) << 6;

    f32x4 acc[4][4];
#pragma unroll
    for (int a = 0; a < 4; ++a)
#pragma unroll
        for (int c = 0; c < 4; ++c) acc[a][c] = (f32x4){0.f, 0.f, 0.f, 0.f};

    const unsigned short* Wrow = Wh + (size_t)(w * 64 + m16) * CD;
    const unsigned short* Xrow = xh + ((size_t)(b * ND + n0 + m16)) * CD;

#pragma unroll
    for (int ks = 0; ks < 8; ++ks) {
        const int ko = ks * 32 + g4 * 8;
        f16x8 af[4], bf[4];
#pragma unroll
        for (int ms = 0; ms < 4; ++ms)
            af[ms] = *reinterpret_cast<const f16x8*>(Wrow + (size_t)ms * 16 * CD + ko);
#pragma unroll
        for (int ns = 0; ns < 4; ++ns)
            bf[ns] = *reinterpret_cast<const f16x8*>(Xrow + (size_t)ns * 16 * CD + ko);
        if (w == 0) {
#pragma unroll
            for (int ms = 0; ms < 4; ++ms)
#pragma unroll
                for (int ns = 0; ns < 4; ++ns)
                    acc[ms][ns] = __builtin_amdgcn_mfma_f32_16x16x32_f16(
                        af[ms], bf[ns], acc[ms][ns], 0, 0, 0);
        } else {
#pragma unroll
            for (int ms = 0; ms < 4; ++ms)
#pragma unroll
                for (int ns = 0; ns < 4; ++ns)
                    acc[ms][ns] = __builtin_amdgcn_mfma_f32_16x16x32_f16(
                        bf[ns], af[ms], acc[ms][ns], 0, 0, 0);
        }
    }

    if (w == 0) {   // Q (ms 0,1) + K (ms 2,3)
#pragma unroll
        for (int ms = 0; ms < 4; ++ms) {
            const int seg = ms * 16;
            const int mb  = seg + g4 * 4;
            const f32x4 bias = (seg < 32) ? *reinterpret_cast<const f32x4*>(bq + mb)
                                          : *reinterpret_cast<const f32x4*>(bk + (mb - 32));
#pragma unroll
            for (int ns = 0; ns < 4; ++ns) {
                const int n = n0 + ns * 16 + m16;
                u16x4 h;
                if (seg < 32) {
#pragma unroll
                    for (int r = 0; r < 4; ++r)
                        h[r] = f2h(fmaxf(acc[ms][ns][r] + bias[r], 0.f) * LOG2E);
                    *reinterpret_cast<u16x4*>(Qt + ((size_t)(b * ND + n)) * CQ + mb) = h;
                } else {
#pragma unroll
                    for (int r = 0; r < 4; ++r)
                        h[r] = f2h(fmaxf(acc[ms][ns][r] + bias[r], 0.f));
                    *reinterpret_cast<u16x4*>(Kt + ((size_t)(b * ND + n)) * CQ + (mb - 32)) = h;
                }
            }
        }
    } else {        // V: D[n][c], rows n = g4*4+r, cols c = m16
        const int cbase = (w - 1) * 64;
#pragma unroll
        for (int ms = 0; ms < 4; ++ms) {
            const int c = cbase + ms * 16 + m16;
            const float bval = bv[c];
#pragma unroll
            for (int ns = 0; ns < 4; ++ns) {
                const int n = n0 + ns * 16 + g4 * 4;
                u16x4 h;
#pragma unroll
                for (int r = 0; r < 4; ++r)
                    h[r] = f2h(fmaxf(acc[ms][ns][r] + bval, 0.f));
                unsigned short* dst = Vp
                    + ((size_t)((b * 128 + (n >> 5)) * 16 + (c >> 4))) * 512
                    + ((((n >> 3) & 3) * 16 + (c & 15)) * 8) + (n & 7);
                *reinterpret_cast<u16x4*>(dst) = h;
            }
        }
    }
}

// ---------------- flash attention: r8 topology, 128-j steps, shuffle-free softmax ----
// grid: NB*64 blocks (b, 64-row i-strip), 512 threads (8 waves, 2 j-groups x 4).
// Group g owns j in [g*2048, +2048), 16 steps of 128 j. One lgkm barrier/step.
__global__ __launch_bounds__(512, 2) void attn_kernel(
    const unsigned short* __restrict__ Qt, const unsigned short* __restrict__ Kt,
    const unsigned short* __restrict__ Vp, const float* __restrict__ x,
    const float* __restrict__ gamma, float* __restrict__ out)
{
    // 0..65535      p_lds   [2 groups][2 buf][64 i][256 B]  (f16, XOR-swizzled)
    // 65536..67583  scales  [2][2][64] f32
    // 67584..67647  flags   [2][2][4]  i32
    // epilogue: Ocomb [64][260] f32 @0 (aliases); mfin@66560 lfin@67072 wfac@67584
    __shared__ __align__(16) unsigned char smem[68096];
    float* scales = reinterpret_cast<float*>(smem + 65536);
    int*   flags  = reinterpret_cast<int*>(smem + 67584);
    float* Ocomb  = reinterpret_cast<float*>(smem);
    float* mfin   = reinterpret_cast<float*>(smem + 66560);  // [2][64]
    float* lfin   = reinterpret_cast<float*>(smem + 67072);  // [2][64]
    float* wfac   = reinterpret_cast<float*>(smem + 67584);  // [2][64]

    const int tid  = threadIdx.x;
    const int lane = tid & 63;
    const int w8   = __builtin_amdgcn_readfirstlane(tid >> 6);
    const int g    = w8 >> 2;       // j-group
    const int ws   = w8 & 3;        // i-strip (QK) / c-slice (PV)
    const int m16  = lane & 15;
    const int g4   = lane >> 4;
    const int wg   = (blockIdx.x & 7) * 32 + (blockIdx.x >> 3);  // XCD swizzle
    const int b    = wg >> 6;
    const int i0   = (wg & 63) << 6;

    // Q as B-operand: col=i=ws*16+m16, k=g4*8+u
    const f16x8 qfrag = *reinterpret_cast<const f16x8*>(
        Qt + ((size_t)(b * ND + i0 + ws * 16 + m16)) * CQ + g4 * 8);
    // K as A-operand from global: row j=m16 (+16*jt), k=g4*8+u
    const unsigned short* kb = Kt + ((size_t)(b * ND + m16)) * CQ + g4 * 8;
    // V B-frags, packed layout: 16B/lane, 1KB/wave contiguous per frag
    const unsigned short* vpc =
        Vp + ((size_t)(b * 128 * 16 + ws * 4)) * 512 + lane * 8;

    f32x4 oacc[4][4];
#pragma unroll
    for (int a = 0; a < 4; ++a)
#pragma unroll
        for (int c = 0; c < 4; ++c) oacc[a][c] = (f32x4){0.f, 0.f, 0.f, 0.f};
    float mrow = -1e30f;
    float lrow = 0.f;    // per-lane PARTIAL row sum (this lane's j's only)
    const f32x4 zero4 = {0.f, 0.f, 0.f, 0.f};

    const int jbase = g * 2048;
    const int irow  = ws * 16 + m16;
    const int iswz  = (m16 & 7) << 4;     // == (irow&7)<<4

    auto LOADK = [&](f16x8 (&kr)[8], int j) {
#pragma unroll
        for (int t = 0; t < 8; ++t)
            kr[t] = *reinterpret_cast<const f16x8*>(kb + (size_t)(j + t * 16) * CQ);
    };

    auto STEP = [&](int k, f16x8 (&kc)[8], f16x8 (&kn)[8]) {
        const int j0  = jbase + k * 128;
        const int par = k & 1;
        unsigned char* pb = smem + g * 32768 + par * 16384;

        // V frags for first 64 j: issue now, consumed post-barrier
        const int jblk0 = j0 >> 5;
        f16x8 vf[2][4];
#pragma unroll
        for (int jh = 0; jh < 2; ++jh)
#pragma unroll
            for (int cs = 0; cs < 4; ++cs)
                vf[jh][cs] = *reinterpret_cast<const f16x8*>(
                    vpc + (size_t)((jblk0 + jh) * 16 + cs) * 512);
        // prefetch next step's K
        const int jn = (k < 15) ? (j0 + 128) : jbase;
        LOADK(kn, jn);

        // ---- QK^T swapped: D[j][i], col=i=irow; lane holds 32 j values ----
        f32x4 s[8];
#pragma unroll
        for (int t = 0; t < 8; ++t)
            s[t] = __builtin_amdgcn_mfma_f32_16x16x32_f16(kc[t], qfrag, zero4, 0, 0, 0);

        // ---- softmax: per-lane local max + ballot (NO shuffles common path) ----
        float pm = s[0][0];
#pragma unroll
        for (int t = 0; t < 8; ++t)
#pragma unroll
            for (int r = 0; r < 4; ++r) pm = fmaxf(pm, s[t][r]);
        float sc = 1.0f;
        int myresc = 0;
        if (__ballot(pm <= mrow + 8.0f) != ~0ull) {
            // rare path: exact row max via cross-lane reduce
            float pr = pm;
            pr = fmaxf(pr, __shfl_xor(pr, 16));
            pr = fmaxf(pr, __shfl_xor(pr, 32));
            const float mnew = fmaxf(mrow, pr);
            sc = fexp2(mrow - mnew);
            mrow = mnew;
            myresc = 1;
        }
        float rs = 0.f;
#pragma unroll
        for (int t = 0; t < 8; ++t)
#pragma unroll
            for (int r = 0; r < 4; ++r) { s[t][r] = fexp2(s[t][r] - mrow); rs += s[t][r]; }
        lrow = lrow * sc + rs;   // partial sum; cross-lane reduce deferred to epilogue

        // ---- P -> LDS (8x ds_write_b64, swizzled, 256B rows) ----
#pragma unroll
        for (int t = 0; t < 8; ++t) {
            u32x2 pw;
            pw[0] = __builtin_bit_cast(unsigned int,
                        __builtin_amdgcn_cvt_pkrtz(s[t][0], s[t][1]));
            pw[1] = __builtin_bit_cast(unsigned int,
                        __builtin_amdgcn_cvt_pkrtz(s[t][2], s[t][3]));
            const int lo = (irow * 256 + t * 32 + g4 * 8) ^ iswz;
            *reinterpret_cast<u32x2*>(pb + lo) = pw;
        }
        if (g4 == 0)   scales[(g * 2 + par) * 64 + irow] = sc;
        if (lane == 0) flags[(g * 2 + par) * 4 + ws] = myresc;

        // V frags for second 64 j (issued before barrier; latency hides)
        f16x8 vf2[2][4];
#pragma unroll
        for (int jh = 0; jh < 2; ++jh)
#pragma unroll
            for (int cs = 0; cs < 4; ++cs)
                vf2[jh][cs] = *reinterpret_cast<const f16x8*>(
                    vpc + (size_t)((jblk0 + 2 + jh) * 16 + cs) * 512);

        BARRIER();   // lgkm-only: P/scale/flag visible; VMEM stays in flight

        // ---- rescale oacc if any row of the group rescaled ----
        const i32x4 fl = *reinterpret_cast<const i32x4*>(flags + (g * 2 + par) * 4);
        const int anyresc = __builtin_amdgcn_readfirstlane(fl[0] | fl[1] | fl[2] | fl[3]);
        if (anyresc) {
#pragma unroll
            for (int is = 0; is < 4; ++is) {
                const f32x4 sr = *reinterpret_cast<const f32x4*>(
                    scales + (g * 2 + par) * 64 + is * 16 + g4 * 4);
#pragma unroll
                for (int r = 0; r < 4; ++r)
#pragma unroll
                    for (int cs = 0; cs < 4; ++cs) oacc[is][cs][r] *= sr[r];
            }
        }

        // ---- PV: P A-frags from LDS, V B-frags in registers ----
        __builtin_amdgcn_s_setprio(1);
#pragma unroll
        for (int jh = 0; jh < 4; ++jh) {
#pragma unroll
            for (int is = 0; is < 4; ++is) {
                const int lo = ((is * 16 + m16) * 256 + jh * 64 + g4 * 16) ^ iswz;
                const f16x8 pf = *reinterpret_cast<const f16x8*>(pb + lo);
                const f16x8 vv = (jh < 2) ? vf[jh][0] : vf2[jh - 2][0];
#pragma unroll
                for (int cs = 0; cs < 4; ++cs) {
                    const f16x8 vb = (jh == 0) ? vf[0][cs] : (jh == 1) ? vf[1][cs]
                                   : (jh == 2) ? vf2[0][cs] : vf2[1][cs];
                    oacc[is][cs] = __builtin_amdgcn_mfma_f32_16x16x32_f16(
                        pf, vb, oacc[is][cs], 0, 0, 0);
                }
                (void)vv;
            }
        }
        __builtin_amdgcn_s_setprio(0);
    };

    f16x8 kA[8], kB[8];
    LOADK(kA, jbase);

#pragma unroll 1
    for (int k2 = 0; k2 < 8; ++k2) {
        STEP(2 * k2,     kA, kB);
        STEP(2 * k2 + 1, kB, kA);
    }

    // ---- epilogue: reduce partial l across g4, then 2-way flash combine ----
    lrow += __shfl_xor(lrow, 16);
    lrow += __shfl_xor(lrow, 32);
    if (g4 == 0) { mfin[g * 64 + irow] = mrow; lfin[g * 64 + irow] = lrow; }
    __syncthreads();

    if (tid < 128) {
        const int gg = tid >> 6, i = tid & 63;
        const float m0 = mfin[i], m1 = mfin[64 + i];
        const float M  = fmaxf(m0, m1);
        const float e0 = fexp2(m0 - M), e1 = fexp2(m1 - M);
        const float den = lfin[i] * e0 + lfin[64 + i] * e1;
        wfac[gg * 64 + i] = ((gg == 0) ? e0 : e1) / den;
    }
    __syncthreads();   // loop LDS dead; Ocomb aliases it from here

    if (g == 0) {
#pragma unroll
        for (int is = 0; is < 4; ++is) {
            const f32x4 f = *reinterpret_cast<const f32x4*>(wfac + is * 16 + g4 * 4);
#pragma unroll
            for (int cs = 0; cs < 4; ++cs)
#pragma unroll
                for (int r = 0; r < 4; ++r)
                    Ocomb[(is * 16 + g4 * 4 + r) * 260 + ws * 64 + cs * 16 + m16] =
                        oacc[is][cs][r] * f[r];
        }
    }
    __syncthreads();
    if (g == 1) {
#pragma unroll
        for (int is = 0; is < 4; ++is) {
            const f32x4 f = *reinterpret_cast<const f32x4*>(wfac + 64 + is * 16 + g4 * 4);
#pragma unroll
            for (int cs = 0; cs < 4; ++cs)
#pragma unroll
                for (int r = 0; r < 4; ++r)
                    Ocomb[(is * 16 + g4 * 4 + r) * 260 + ws * 64 + cs * 16 + m16] +=
                        oacc[is][cs][r] * f[r];
        }
    }
    __syncthreads();

    const float gm = gamma[0];
#pragma unroll
    for (int pass = 0; pass < 8; ++pass) {
        const int c  = (tid >> 4) + pass * 32;
        const int ib = (tid & 15) * 4;
        f32x4 o;
#pragma unroll
        for (int u = 0; u < 4; ++u) o[u] = Ocomb[(ib + u) * 260 + c];
        const size_t idx = ((size_t)(b * CD + c)) * ND + i0 + ib;
        const f32x4 xv = *reinterpret_cast<const f32x4*>(x + idx);
        f32x4 res;
#pragma unroll
        for (int u = 0; u < 4; ++u) res[u] = gm * o[u] + xv[u];
        *reinterpret_cast<f32x4*>(out + idx) = res;
    }
}

extern "C" void kernel_launch(void* const* d_in, const int* in_sizes, int n_in,
                              void* d_out, int out_size, void* d_ws, size_t ws_size,
                              hipStream_t stream) {
    const float* x     = (const float*)d_in[0];
    const float* wq    = (const float*)d_in[1];
    const float* bq    = (const float*)d_in[2];
    const float* wk    = (const float*)d_in[3];
    const float* bk    = (const float*)d_in[4];
    const float* wv    = (const float*)d_in[5];
    const float* bv    = (const float*)d_in[6];
    const float* gamma = (const float*)d_in[7];

    unsigned short* Qt = (unsigned short*)d_ws;               // 1MB (scaled by log2e)
    unsigned short* Kt = Qt + (size_t)NB * ND * CQ;           // 1MB
    unsigned short* Vp = Kt + (size_t)NB * ND * CQ;           // 8MB packed frags
    unsigned short* Wh = Vp + (size_t)NB * CD * ND;           // 160KB
    unsigned short* xh = Wh + (size_t)320 * CD;               // 8MB
    float* out = (float*)d_out;

    cvt_kernel<<<dim3(1104),     dim3(256), 0, stream>>>(x, wq, wk, wv, xh, Wh);
    proj_kernel<<<dim3(NB * 64), dim3(320), 0, stream>>>(Wh, xh, bq, bk, bv, Qt, Kt, Vp);
    attn_kernel<<<dim3(NB * 64), dim3(512), 0, stream>>>(Qt, Kt, Vp, x, gamma, out);
}

// Round 11
// 71.715 us; speedup vs baseline: 3.3790x; 1.3198x over previous
//
#include <hip/hip_runtime.h>
#include <stdint.h>

// SelfAttentionBlock: B=4, C=256, H=W=64 (N=4096), CQK=32.
//   cvt : W fp32->f16 (Wh) + x -> f16 transposed xh[b][n][c]
//   proj: register MFMA GEMM -> Qt[n][32]*log2e, Kt[n][32],
//         Vp = V pre-packed in PV B-fragment order [b][jblk][ct][lane][8]
//   attn: r8 structure (512 thr, 2 j-groups x 4 waves, 64-j steps, V direct
//         from L2 via Vp, K reg prefetch, P dbuf in LDS) with two changes:
//         (1) per-step sync is GROUP-LOCAL (monotonic LDS counter + spin),
//             not block-wide s_barrier -> the two j-groups drift out of phase
//             so each SIMD overlaps one VALU-phase wave with one MFMA-phase wave;
//         (2) shuffle-free common-path softmax (ballot defer-max; per-lane
//             partial l reduced once in epilogue).

#define NB 4
#define CD 256
#define ND 4096
#define CQ 32
#define LOG2E 1.4426950408889634f

typedef __attribute__((ext_vector_type(4))) float f32x4;
typedef __attribute__((ext_vector_type(8))) _Float16 f16x8;
typedef __attribute__((ext_vector_type(4))) unsigned short u16x4;
typedef __attribute__((ext_vector_type(8))) unsigned short u16x8;
typedef __attribute__((ext_vector_type(2))) unsigned int u32x2;
typedef __attribute__((ext_vector_type(4))) int i32x4;

static __device__ __forceinline__ unsigned short f2h(float f) {
    union { _Float16 h; unsigned short u; } cv; cv.h = (_Float16)f; return cv.u;
}
static __device__ __forceinline__ float fexp2(float xv) {
    float r; asm("v_exp_f32 %0, %1" : "=v"(r) : "v"(xv)); return r;
}

// ---------------- fused cvt: W fp32->f16 and x -> xh[b][n][c] f16 ----------------
__global__ __launch_bounds__(256) void cvt_kernel(
    const float* __restrict__ x,
    const float* __restrict__ wq, const float* __restrict__ wk,
    const float* __restrict__ wv,
    unsigned short* __restrict__ xh, unsigned short* __restrict__ Wh)
{
    __shared__ unsigned short xt[64 * 72];
    if (blockIdx.x >= 1024) {   // wcvt (80 blocks)
        const int idx = (blockIdx.x - 1024) * 256 + threadIdx.x;
        const int m = idx >> 6, kq = (idx & 63) << 2;
        const float* src = (m < 32) ? (wq + (size_t)m * CD + kq)
                         : (m < 64) ? (wk + (size_t)(m - 32) * CD + kq)
                                    : (wv + (size_t)(m - 64) * CD + kq);
        const f32x4 v = *reinterpret_cast<const f32x4*>(src);
        u16x4 h;
#pragma unroll
        for (int u = 0; u < 4; ++u) h[u] = f2h(v[u]);
        *reinterpret_cast<u16x4*>(Wh + (size_t)m * CD + kq) = h;
        return;
    }
    const int t  = threadIdx.x;
    const int nt = blockIdx.x & 63, ct = (blockIdx.x >> 6) & 3, b = blockIdx.x >> 8;
    const int n0 = nt << 6, c0 = ct << 6;

    const float* xb = x + ((size_t)(b * CD + c0)) * ND + n0;
#pragma unroll
    for (int s = t; s < 1024; s += 256) {
        const int c = s >> 4, nq = (s & 15) << 2;
        const f32x4 v = *reinterpret_cast<const f32x4*>(xb + (size_t)c * ND + nq);
        u16x4 h;
#pragma unroll
        for (int u = 0; u < 4; ++u) h[u] = f2h(v[u]);
        *reinterpret_cast<u16x4*>(&xt[c * 72 + nq]) = h;
    }
    __syncthreads();

    const int n = t >> 2, cb = (t & 3) << 4;
    u16x8 o0, o1;
#pragma unroll
    for (int u = 0; u < 8; ++u) o0[u] = xt[(cb + u) * 72 + n];
#pragma unroll
    for (int u = 0; u < 8; ++u) o1[u] = xt[(cb + 8 + u) * 72 + n];
    unsigned short* dst = xh + ((size_t)(b * ND + n0 + n)) * CD + c0 + cb;
    *reinterpret_cast<u16x8*>(dst)     = o0;
    *reinterpret_cast<u16x8*>(dst + 8) = o1;
}

// ---------------- projection: register MFMA GEMM ----------------
// wave 0: Q,K rows (D[c][n]); waves 1-4: V rows with swapped operands
// (D[n][c]) so each lane's 4 acc values are consecutive n -> one u16x4
// store into the Vp packed-fragment layout.
__global__ __launch_bounds__(320) void proj_kernel(
    const unsigned short* __restrict__ Wh, const unsigned short* __restrict__ xh,
    const float* __restrict__ bq, const float* __restrict__ bk,
    const float* __restrict__ bv,
    unsigned short* __restrict__ Qt, unsigned short* __restrict__ Kt,
    unsigned short* __restrict__ Vp)
{
    const int tid = threadIdx.x;
    const int lane = tid & 63;
    const int w = __builtin_amdgcn_readfirstlane(tid >> 6);
    const int m16 = lane & 15, g4 = lane >> 4;
    const int b = blockIdx.x >> 6, n0 = (blockIdx.x & 63) << 6;

    f32x4 acc[4][4];
#pragma unroll
    for (int a = 0; a < 4; ++a)
#pragma unroll
        for (int c = 0; c < 4; ++c) acc[a][c] = (f32x4){0.f, 0.f, 0.f, 0.f};

    const unsigned short* Wrow = Wh + (size_t)(w * 64 + m16) * CD;
    const unsigned short* Xrow = xh + ((size_t)(b * ND + n0 + m16)) * CD;

#pragma unroll
    for (int ks = 0; ks < 8; ++ks) {
        const int ko = ks * 32 + g4 * 8;
        f16x8 af[4], bf[4];
#pragma unroll
        for (int ms = 0; ms < 4; ++ms)
            af[ms] = *reinterpret_cast<const f16x8*>(Wrow + (size_t)ms * 16 * CD + ko);
#pragma unroll
        for (int ns = 0; ns < 4; ++ns)
            bf[ns] = *reinterpret_cast<const f16x8*>(Xrow + (size_t)ns * 16 * CD + ko);
        if (w == 0) {
#pragma unroll
            for (int ms = 0; ms < 4; ++ms)
#pragma unroll
                for (int ns = 0; ns < 4; ++ns)
                    acc[ms][ns] = __builtin_amdgcn_mfma_f32_16x16x32_f16(
                        af[ms], bf[ns], acc[ms][ns], 0, 0, 0);
        } else {
#pragma unroll
            for (int ms = 0; ms < 4; ++ms)
#pragma unroll
                for (int ns = 0; ns < 4; ++ns)
                    acc[ms][ns] = __builtin_amdgcn_mfma_f32_16x16x32_f16(
                        bf[ns], af[ms], acc[ms][ns], 0, 0, 0);
        }
    }

    if (w == 0) {   // Q (ms 0,1) + K (ms 2,3)
#pragma unroll
        for (int ms = 0; ms < 4; ++ms) {
            const int seg = ms * 16;
            const int mb  = seg + g4 * 4;
            const f32x4 bias = (seg < 32) ? *reinterpret_cast<const f32x4*>(bq + mb)
                                          : *reinterpret_cast<const f32x4*>(bk + (mb - 32));
#pragma unroll
            for (int ns = 0; ns < 4; ++ns) {
                const int n = n0 + ns * 16 + m16;
                u16x4 h;
                if (seg < 32) {
#pragma unroll
                    for (int r = 0; r < 4; ++r)
                        h[r] = f2h(fmaxf(acc[ms][ns][r] + bias[r], 0.f) * LOG2E);
                    *reinterpret_cast<u16x4*>(Qt + ((size_t)(b * ND + n)) * CQ + mb) = h;
                } else {
#pragma unroll
                    for (int r = 0; r < 4; ++r)
                        h[r] = f2h(fmaxf(acc[ms][ns][r] + bias[r], 0.f));
                    *reinterpret_cast<u16x4*>(Kt + ((size_t)(b * ND + n)) * CQ + (mb - 32)) = h;
                }
            }
        }
    } else {        // V: D[n][c], rows n = g4*4+r, cols c = m16
        const int cbase = (w - 1) * 64;
#pragma unroll
        for (int ms = 0; ms < 4; ++ms) {
            const int c = cbase + ms * 16 + m16;
            const float bval = bv[c];
#pragma unroll
            for (int ns = 0; ns < 4; ++ns) {
                const int n = n0 + ns * 16 + g4 * 4;
                u16x4 h;
#pragma unroll
                for (int r = 0; r < 4; ++r)
                    h[r] = f2h(fmaxf(acc[ms][ns][r] + bval, 0.f));
                unsigned short* dst = Vp
                    + ((size_t)((b * 128 + (n >> 5)) * 16 + (c >> 4))) * 512
                    + ((((n >> 3) & 3) * 16 + (c & 15)) * 8) + (n & 7);
                *reinterpret_cast<u16x4*>(dst) = h;
            }
        }
    }
}

// ---------------- flash attention: r8 + group-local sync + shuffle-free softmax ----
// grid: NB*64 blocks (b, 64-row i-strip), 512 threads (8 waves, 2 j-groups x 4).
// Group g owns j in [g*2048, +2048), 32 steps of 64 j. Per-step sync is a
// group-local monotonic LDS counter (atomicAdd + spin) - no block barrier.
__global__ __launch_bounds__(512, 2) void attn_kernel(
    const unsigned short* __restrict__ Qt, const unsigned short* __restrict__ Kt,
    const unsigned short* __restrict__ Vp, const float* __restrict__ x,
    const float* __restrict__ gamma, float* __restrict__ out)
{
    // 0..32767      p_lds   [2 groups][2 buf][64 i][128 B]  (f16, XOR-swizzled)
    // 32768..34815  scales  [2][2][64] f32
    // 34816..34879  flags   [2][2][4]  i32
    // epilogue: Ocomb [64][260] f32 @0 (aliases); mfin@66560 lfin@67072 wfac@67584
    __shared__ __align__(16) unsigned char smem[68096];
    __shared__ int gctr[2];
    float* scales = reinterpret_cast<float*>(smem + 32768);
    int*   flags  = reinterpret_cast<int*>(smem + 34816);
    float* Ocomb  = reinterpret_cast<float*>(smem);
    float* mfin   = reinterpret_cast<float*>(smem + 66560);  // [2][64]
    float* lfin   = reinterpret_cast<float*>(smem + 67072);  // [2][64]
    float* wfac   = reinterpret_cast<float*>(smem + 67584);  // [2][64]

    const int tid  = threadIdx.x;
    const int lane = tid & 63;
    const int w8   = __builtin_amdgcn_readfirstlane(tid >> 6);
    const int g    = w8 >> 2;       // j-group
    const int ws   = w8 & 3;        // i-strip (QK) / c-slice (PV)
    const int m16  = lane & 15;
    const int g4   = lane >> 4;
    const int wg   = (blockIdx.x & 7) * 32 + (blockIdx.x >> 3);  // XCD swizzle
    const int b    = wg >> 6;
    const int i0   = (wg & 63) << 6;

    if (tid < 2) gctr[tid] = 0;
    __syncthreads();   // counter init visible before any bump

    // Q as B-operand: col=i=ws*16+m16, k=g4*8+u
    const f16x8 qfrag = *reinterpret_cast<const f16x8*>(
        Qt + ((size_t)(b * ND + i0 + ws * 16 + m16)) * CQ + g4 * 8);
    // K as A-operand from global: row j=m16 (+16*jt), k=g4*8+u
    const unsigned short* kb = Kt + ((size_t)(b * ND + m16)) * CQ + g4 * 8;
    // V B-frags, packed layout: 16B/lane, 1KB/wave contiguous per frag
    const unsigned short* vpc =
        Vp + ((size_t)(b * 128 * 16 + ws * 4)) * 512 + lane * 8;

    f32x4 oacc[4][4];
#pragma unroll
    for (int a = 0; a < 4; ++a)
#pragma unroll
        for (int c = 0; c < 4; ++c) oacc[a][c] = (f32x4){0.f, 0.f, 0.f, 0.f};
    float mrow = -1e30f;
    float lrow = 0.f;    // per-lane PARTIAL row sum; reduced in epilogue
    const f32x4 zero4 = {0.f, 0.f, 0.f, 0.f};

    const int jbase = g * 2048;
    const int irow  = ws * 16 + m16;
    const int iswz  = (m16 & 7) << 4;     // == (irow&7)<<4

    auto LOADK = [&](f16x8 (&kr)[4], int j) {
#pragma unroll
        for (int t = 0; t < 4; ++t)
            kr[t] = *reinterpret_cast<const f16x8*>(kb + (size_t)(j + t * 16) * CQ);
    };

    // group-local sync: wave bumps after its P-write is drained; spin until
    // all 4 waves of the group reached step k. Monotonic counter, no reset.
    auto GSYNC = [&](int k) {
        asm volatile("s_waitcnt lgkmcnt(0)" ::: "memory");
        if (lane == 0) atomicAdd(&gctr[g], 1);
        const int tgt = (k + 1) * 4;
        int cv;
        do {
            __builtin_amdgcn_s_sleep(1);
            cv = __builtin_amdgcn_readfirstlane(*(volatile int*)&gctr[g]);
        } while (cv < tgt);
    };

    auto STEP = [&](int k, f16x8 (&kc)[4], f16x8 (&kn)[4]) {
        const int j0  = jbase + k * 64;
        const int par = k & 1;
        unsigned char* pb = smem + g * 16384 + par * 8192;

        // issue V frag loads now; consumed after the sync (latency hidden)
        const int jblk0 = j0 >> 5;
        f16x8 vf[2][4];
#pragma unroll
        for (int jh = 0; jh < 2; ++jh)
#pragma unroll
            for (int cs = 0; cs < 4; ++cs)
                vf[jh][cs] = *reinterpret_cast<const f16x8*>(
                    vpc + (size_t)((jblk0 + jh) * 16 + cs) * 512);
        // prefetch next step's K
        const int jn = (k < 31) ? (j0 + 64) : jbase;
        LOADK(kn, jn);

        // ---- QK^T swapped: D[j][i], col=i=irow, lane holds 16 j values ----
        f32x4 s[4];
#pragma unroll
        for (int t = 0; t < 4; ++t)
            s[t] = __builtin_amdgcn_mfma_f32_16x16x32_f16(kc[t], qfrag, zero4, 0, 0, 0);

        // ---- softmax (log2 domain): shuffle-free common path ----
        float pm = s[0][0];
#pragma unroll
        for (int t = 0; t < 4; ++t)
#pragma unroll
            for (int r = 0; r < 4; ++r) pm = fmaxf(pm, s[t][r]);
        float sc = 1.0f;
        int myresc = 0;
        if (__ballot(pm <= mrow + 8.0f) != ~0ull) {
            // rare path: exact row max via cross-lane reduce
            float pr = fmaxf(pm, __shfl_xor(pm, 16));
            pr = fmaxf(pr, __shfl_xor(pr, 32));
            const float mnew = fmaxf(mrow, pr);
            sc = fexp2(mrow - mnew);
            mrow = mnew;
            myresc = 1;
        }
        float rs = 0.f;
#pragma unroll
        for (int t = 0; t < 4; ++t)
#pragma unroll
            for (int r = 0; r < 4; ++r) { s[t][r] = fexp2(s[t][r] - mrow); rs += s[t][r]; }
        lrow = lrow * sc + rs;   // per-lane partial; cross-lane reduce in epilogue

        // ---- P -> LDS (4x ds_write_b64, swizzled) + scale + flag ----
#pragma unroll
        for (int t = 0; t < 4; ++t) {
            u32x2 pw;
            pw[0] = __builtin_bit_cast(unsigned int,
                        __builtin_amdgcn_cvt_pkrtz(s[t][0], s[t][1]));
            pw[1] = __builtin_bit_cast(unsigned int,
                        __builtin_amdgcn_cvt_pkrtz(s[t][2], s[t][3]));
            const int lo = (irow * 128 + t * 32 + g4 * 8) ^ iswz;
            *reinterpret_cast<u32x2*>(pb + lo) = pw;
        }
        if (g4 == 0)   scales[(g * 2 + par) * 64 + irow] = sc;
        if (lane == 0) flags[(g * 2 + par) * 4 + ws] = myresc;

        GSYNC(k);   // group-local; other j-group unconstrained

        // ---- rescale oacc if any row of the group rescaled ----
        const i32x4 fl = *reinterpret_cast<const i32x4*>(flags + (g * 2 + par) * 4);
        const int anyresc = __builtin_amdgcn_readfirstlane(fl[0] | fl[1] | fl[2] | fl[3]);
        if (anyresc) {
#pragma unroll
            for (int is = 0; is < 4; ++is) {
                const f32x4 sr = *reinterpret_cast<const f32x4*>(
                    scales + (g * 2 + par) * 64 + is * 16 + g4 * 4);
#pragma unroll
                for (int r = 0; r < 4; ++r)
#pragma unroll
                    for (int cs = 0; cs < 4; ++cs) oacc[is][cs][r] *= sr[r];
            }
        }

        // ---- PV: P A-frags from LDS, V B-frags in registers ----
        __builtin_amdgcn_s_setprio(1);
#pragma unroll
        for (int jh = 0; jh < 2; ++jh) {
#pragma unroll
            for (int is = 0; is < 4; ++is) {
                const int lo = ((is * 16 + m16) * 128 + jh * 64 + g4 * 16) ^ iswz;
                const f16x8 pf = *reinterpret_cast<const f16x8*>(pb + lo);
#pragma unroll
                for (int cs = 0; cs < 4; ++cs)
                    oacc[is][cs] = __builtin_amdgcn_mfma_f32_16x16x32_f16(
                        pf, vf[jh][cs], oacc[is][cs], 0, 0, 0);
            }
        }
        __builtin_amdgcn_s_setprio(0);
    };

    f16x8 kA[4], kB[4];
    LOADK(kA, jbase);

#pragma unroll 1
    for (int k2 = 0; k2 < 16; ++k2) {
        STEP(2 * k2,     kA, kB);
        STEP(2 * k2 + 1, kB, kA);
    }

    // ---- epilogue: reduce partial l across lanes, then 2-way flash combine ----
    lrow += __shfl_xor(lrow, 16);
    lrow += __shfl_xor(lrow, 32);
    if (g4 == 0) { mfin[g * 64 + irow] = mrow; lfin[g * 64 + irow] = lrow; }
    __syncthreads();

    if (tid < 128) {
        const int gg = tid >> 6, i = tid & 63;
        const float m0 = mfin[i], m1 = mfin[64 + i];
        const float M  = fmaxf(m0, m1);
        const float e0 = fexp2(m0 - M), e1 = fexp2(m1 - M);
        const float den = lfin[i] * e0 + lfin[64 + i] * e1;
        wfac[gg * 64 + i] = ((gg == 0) ? e0 : e1) / den;
    }
    __syncthreads();   // loop LDS dead; Ocomb aliases it from here

    if (g == 0) {
#pragma unroll
        for (int is = 0; is < 4; ++is) {
            const f32x4 f = *reinterpret_cast<const f32x4*>(wfac + is * 16 + g4 * 4);
#pragma unroll
            for (int cs = 0; cs < 4; ++cs)
#pragma unroll
                for (int r = 0; r < 4; ++r)
                    Ocomb[(is * 16 + g4 * 4 + r) * 260 + ws * 64 + cs * 16 + m16] =
                        oacc[is][cs][r] * f[r];
        }
    }
    __syncthreads();
    if (g == 1) {
#pragma unroll
        for (int is = 0; is < 4; ++is) {
            const f32x4 f = *reinterpret_cast<const f32x4*>(wfac + 64 + is * 16 + g4 * 4);
#pragma unroll
            for (int cs = 0; cs < 4; ++cs)
#pragma unroll
                for (int r = 0; r < 4; ++r)
                    Ocomb[(is * 16 + g4 * 4 + r) * 260 + ws * 64 + cs * 16 + m16] +=
                        oacc[is][cs][r] * f[r];
        }
    }
    __syncthreads();

    const float gm = gamma[0];
#pragma unroll
    for (int pass = 0; pass < 8; ++pass) {
        const int c  = (tid >> 4) + pass * 32;
        const int ib = (tid & 15) * 4;
        f32x4 o;
#pragma unroll
        for (int u = 0; u < 4; ++u) o[u] = Ocomb[(ib + u) * 260 + c];
        const size_t idx = ((size_t)(b * CD + c)) * ND + i0 + ib;
        const f32x4 xv = *reinterpret_cast<const f32x4*>(x + idx);
        f32x4 res;
#pragma unroll
        for (int u = 0; u < 4; ++u) res[u] = gm * o[u] + xv[u];
        *reinterpret_cast<f32x4*>(out + idx) = res;
    }
}

extern "C" void kernel_launch(void* const* d_in, const int* in_sizes, int n_in,
                              void* d_out, int out_size, void* d_ws, size_t ws_size,
                              hipStream_t stream) {
    const float* x     = (const float*)d_in[0];
    const float* wq    = (const float*)d_in[1];
    const float* bq    = (const float*)d_in[2];
    const float* wk    = (const float*)d_in[3];
    const float* bk    = (const float*)d_in[4];
    const float* wv    = (const float*)d_in[5];
    const float* bv    = (const float*)d_in[6];
    const float* gamma = (const float*)d_in[7];

    unsigned short* Qt = (unsigned short*)d_ws;               // 1MB (scaled by log2e)
    unsigned short* Kt = Qt + (size_t)NB * ND * CQ;           // 1MB
    unsigned short* Vp = Kt + (size_t)NB * ND * CQ;           // 8MB packed frags
    unsigned short* Wh = Vp + (size_t)NB * CD * ND;           // 160KB
    unsigned short* xh = Wh + (size_t)320 * CD;               // 8MB
    float* out = (float*)d_out;

    cvt_kernel<<<dim3(1104),     dim3(256), 0, stream>>>(x, wq, wk, wv, xh, Wh);
    proj_kernel<<<dim3(NB * 64), dim3(320), 0, stream>>>(Wh, xh, bq, bk, bv, Qt, Kt, Vp);
    attn_kernel<<<dim3(NB * 64), dim3(512), 0, stream>>>(Qt, Kt, Vp, x, gamma, out);
}

// Round 12
// 68.127 us; speedup vs baseline: 3.5569x; 1.0527x over previous
//
#include <hip/hip_runtime.h>
#include <stdint.h>

// SelfAttentionBlock: B=4, C=256, H=W=64 (N=4096), CQK=32.
//   wcvt: W fp32->f16 (Wh), 80 blocks.
//   proj: x-transpose fused in-kernel (32KB swizzled LDS) + register MFMA GEMM
//         -> Qt[n][32]*log2e, Kt[n][32], Vp packed PV-B-fragment order.
//   attn: flash attention, 768 thr = 3 j-groups x 4 waves = 3 waves/SIMD.
//         Per-wave structure = r11: V direct from L2 (Vp frags), K reg
//         prefetch, swapped QK^T, shuffle-free defer-max softmax (log2),
//         per-lane partial l, P dbuf in LDS, group-local counter sync
//         (no block barrier in loop). 3-way flash combine in epilogue.

#define NB 4
#define CD 256
#define ND 4096
#define CQ 32
#define LOG2E 1.4426950408889634f

typedef __attribute__((ext_vector_type(4))) float f32x4;
typedef __attribute__((ext_vector_type(8))) _Float16 f16x8;
typedef __attribute__((ext_vector_type(4))) unsigned short u16x4;
typedef __attribute__((ext_vector_type(2))) unsigned int u32x2;
typedef __attribute__((ext_vector_type(4))) int i32x4;

static __device__ __forceinline__ unsigned short f2h(float f) {
    union { _Float16 h; unsigned short u; } cv; cv.h = (_Float16)f; return cv.u;
}
static __device__ __forceinline__ float fexp2(float xv) {
    float r; asm("v_exp_f32 %0, %1" : "=v"(r) : "v"(xv)); return r;
}

// ---------------- wcvt: W fp32 -> f16 ----------------
__global__ __launch_bounds__(256) void wcvt_kernel(
    const float* __restrict__ wq, const float* __restrict__ wk,
    const float* __restrict__ wv, unsigned short* __restrict__ Wh)
{
    const int idx = blockIdx.x * 256 + threadIdx.x;   // 80 blocks
    const int m = idx >> 6, kq = (idx & 63) << 2;
    const float* src = (m < 32) ? (wq + (size_t)m * CD + kq)
                     : (m < 64) ? (wk + (size_t)(m - 32) * CD + kq)
                                : (wv + (size_t)(m - 64) * CD + kq);
    const f32x4 v = *reinterpret_cast<const f32x4*>(src);
    u16x4 h;
#pragma unroll
    for (int u = 0; u < 4; ++u) h[u] = f2h(v[u]);
    *reinterpret_cast<u16x4*>(Wh + (size_t)m * CD + kq) = h;
}

// ---------------- projection: fused x-transpose + register MFMA GEMM ----------------
// grid NB*64 (b, 64-n tile), 320 threads = 5 waves.
// Phase 1: x[b][0:256][n0:n0+64] f32 -> xls[n][c] f16 in LDS (XOR-swizzled).
// Phase 2: wave 0 computes Q,K (D[c][n]); waves 1-4 V with swapped operands
// (D[n][c]) -> packed Vp store.
__global__ __launch_bounds__(320) void proj_kernel(
    const float* __restrict__ x, const unsigned short* __restrict__ Wh,
    const float* __restrict__ bq, const float* __restrict__ bk,
    const float* __restrict__ bv,
    unsigned short* __restrict__ Qt, unsigned short* __restrict__ Kt,
    unsigned short* __restrict__ Vp)
{
    __shared__ __align__(16) unsigned char xls[64 * 512];   // 32KB: [n][c] f16 swizzled

    const int tid = threadIdx.x;
    const int lane = tid & 63;
    const int w = __builtin_amdgcn_readfirstlane(tid >> 6);
    const int m16 = lane & 15, g4 = lane >> 4;
    const int b = blockIdx.x >> 6, n0 = (blockIdx.x & 63) << 6;

    {   // phase 1: load + transpose-convert into LDS
        const float* xb = x + (size_t)b * CD * ND + n0;
#pragma unroll 1
        for (int idx = tid; idx < 4096; idx += 320) {
            const int c = idx >> 4, nq = (idx & 15) << 2;
            const f32x4 v = *reinterpret_cast<const f32x4*>(xb + (size_t)c * ND + nq);
#pragma unroll
            for (int r = 0; r < 4; ++r) {
                const int row = nq + r;
                const int ad = (row * 512 + c * 2) ^ ((row & 7) << 4);
                *reinterpret_cast<unsigned short*>(&xls[ad]) = f2h(v[r]);
            }
        }
    }
    __syncthreads();

    f32x4 acc[4][4];
#pragma unroll
    for (int a = 0; a < 4; ++a)
#pragma unroll
        for (int c = 0; c < 4; ++c) acc[a][c] = (f32x4){0.f, 0.f, 0.f, 0.f};

    const unsigned short* Wrow = Wh + (size_t)(w * 64 + m16) * CD;
    const int bswz = (m16 & 7) << 4;

#pragma unroll
    for (int ks = 0; ks < 8; ++ks) {
        const int ko = ks * 32 + g4 * 8;
        f16x8 af[4], bf[4];
#pragma unroll
        for (int ms = 0; ms < 4; ++ms)
            af[ms] = *reinterpret_cast<const f16x8*>(Wrow + (size_t)ms * 16 * CD + ko);
#pragma unroll
        for (int ns = 0; ns < 4; ++ns) {
            const int ad = ((ns * 16 + m16) * 512 + ko * 2) ^ bswz;
            bf[ns] = *reinterpret_cast<const f16x8*>(&xls[ad]);
        }
        if (w == 0) {
#pragma unroll
            for (int ms = 0; ms < 4; ++ms)
#pragma unroll
                for (int ns = 0; ns < 4; ++ns)
                    acc[ms][ns] = __builtin_amdgcn_mfma_f32_16x16x32_f16(
                        af[ms], bf[ns], acc[ms][ns], 0, 0, 0);
        } else {
#pragma unroll
            for (int ms = 0; ms < 4; ++ms)
#pragma unroll
                for (int ns = 0; ns < 4; ++ns)
                    acc[ms][ns] = __builtin_amdgcn_mfma_f32_16x16x32_f16(
                        bf[ns], af[ms], acc[ms][ns], 0, 0, 0);
        }
    }

    if (w == 0) {   // Q (ms 0,1) + K (ms 2,3): D[c][n], col = m16 = n
#pragma unroll
        for (int ms = 0; ms < 4; ++ms) {
            const int seg = ms * 16;
            const int mb  = seg + g4 * 4;
            const f32x4 bias = (seg < 32) ? *reinterpret_cast<const f32x4*>(bq + mb)
                                          : *reinterpret_cast<const f32x4*>(bk + (mb - 32));
#pragma unroll
            for (int ns = 0; ns < 4; ++ns) {
                const int n = n0 + ns * 16 + m16;
                u16x4 h;
                if (seg < 32) {
#pragma unroll
                    for (int r = 0; r < 4; ++r)
                        h[r] = f2h(fmaxf(acc[ms][ns][r] + bias[r], 0.f) * LOG2E);
                    *reinterpret_cast<u16x4*>(Qt + ((size_t)(b * ND + n)) * CQ + mb) = h;
                } else {
#pragma unroll
                    for (int r = 0; r < 4; ++r)
                        h[r] = f2h(fmaxf(acc[ms][ns][r] + bias[r], 0.f));
                    *reinterpret_cast<u16x4*>(Kt + ((size_t)(b * ND + n)) * CQ + (mb - 32)) = h;
                }
            }
        }
    } else {        // V: D[n][c], rows n = g4*4+r, cols c = m16
        const int cbase = (w - 1) * 64;
#pragma unroll
        for (int ms = 0; ms < 4; ++ms) {
            const int c = cbase + ms * 16 + m16;
            const float bval = bv[c];
#pragma unroll
            for (int ns = 0; ns < 4; ++ns) {
                const int n = n0 + ns * 16 + g4 * 4;
                u16x4 h;
#pragma unroll
                for (int r = 0; r < 4; ++r)
                    h[r] = f2h(fmaxf(acc[ms][ns][r] + bval, 0.f));
                unsigned short* dst = Vp
                    + ((size_t)((b * 128 + (n >> 5)) * 16 + (c >> 4))) * 512
                    + ((((n >> 3) & 3) * 16 + (c & 15)) * 8) + (n & 7);
                *reinterpret_cast<u16x4*>(dst) = h;
            }
        }
    }
}

// ---------------- flash attention: 3 j-groups x 4 waves, group-local sync ----------------
// grid: NB*64 blocks (b, 64-row i-strip), 768 threads (12 waves, 3 waves/SIMD).
// Group g owns 64-j chunks [cbase[g], cbase[g+1]) of 64 chunks total (22/21/21).
__global__ __launch_bounds__(768) void attn_kernel(
    const unsigned short* __restrict__ Qt, const unsigned short* __restrict__ Kt,
    const unsigned short* __restrict__ Vp, const float* __restrict__ x,
    const float* __restrict__ gamma, float* __restrict__ out)
{
    // 0..49151      p_lds   [3 groups][2 buf][64 i][128 B]  (f16, XOR-swizzled)
    // 49152..50687  scales  [3][2][64] f32
    // 50688..50783  flags   [3][2][4]  i32
    // epilogue: Ocomb [64][260] f32 @0 (aliases); mfin@66560 lfin@67328 wfac@68096
    __shared__ __align__(16) unsigned char smem[68864];
    __shared__ int gctr[3];
    float* scales = reinterpret_cast<float*>(smem + 49152);
    int*   flags  = reinterpret_cast<int*>(smem + 50688);
    float* Ocomb  = reinterpret_cast<float*>(smem);
    float* mfin   = reinterpret_cast<float*>(smem + 66560);  // [3][64]
    float* lfin   = reinterpret_cast<float*>(smem + 67328);  // [3][64]
    float* wfac   = reinterpret_cast<float*>(smem + 68096);  // [3][64]

    const int tid  = threadIdx.x;
    const int lane = tid & 63;
    const int w12  = __builtin_amdgcn_readfirstlane(tid >> 6);
    const int g    = (w12 >= 8) ? 2 : (w12 >> 2);   // groups: waves 0-3,4-7,8-11
    const int ws   = (w12 >= 8) ? (w12 - 8) : (w12 & 3);
    const int m16  = lane & 15;
    const int g4   = lane >> 4;
    const int wg   = (blockIdx.x & 7) * 32 + (blockIdx.x >> 3);  // XCD swizzle
    const int b    = wg >> 6;
    const int i0   = (wg & 63) << 6;

    if (tid < 3) gctr[tid] = 0;
    __syncthreads();   // counter init visible before any bump

    // Q as B-operand: col=i=ws*16+m16, k=g4*8+u
    const f16x8 qfrag = *reinterpret_cast<const f16x8*>(
        Qt + ((size_t)(b * ND + i0 + ws * 16 + m16)) * CQ + g4 * 8);
    // K as A-operand from global: row j=m16 (+16*jt), k=g4*8+u
    const unsigned short* kb = Kt + ((size_t)(b * ND + m16)) * CQ + g4 * 8;
    // V B-frags, packed layout: 16B/lane, 1KB/wave contiguous per frag
    const unsigned short* vpc =
        Vp + ((size_t)(b * 128 * 16 + ws * 4)) * 512 + lane * 8;

    f32x4 oacc[4][4];
#pragma unroll
    for (int a = 0; a < 4; ++a)
#pragma unroll
        for (int c = 0; c < 4; ++c) oacc[a][c] = (f32x4){0.f, 0.f, 0.f, 0.f};
    float mrow = -1e30f;
    float lrow = 0.f;    // per-lane PARTIAL row sum; reduced in epilogue
    const f32x4 zero4 = {0.f, 0.f, 0.f, 0.f};

    const int cbase  = (g == 0) ? 0 : (g == 1) ? 22 : 43;
    const int nsteps = (g == 0) ? 22 : 21;
    const int irow   = ws * 16 + m16;
    const int iswz   = (m16 & 7) << 4;

    auto LOADK = [&](f16x8 (&kr)[4], int j) {
#pragma unroll
        for (int t = 0; t < 4; ++t)
            kr[t] = *reinterpret_cast<const f16x8*>(kb + (size_t)(j + t * 16) * CQ);
    };

    // group-local sync: bump after P-write drained; spin till all 4 group waves arrive.
    auto GSYNC = [&](int s) {
        asm volatile("s_waitcnt lgkmcnt(0)" ::: "memory");
        if (lane == 0) atomicAdd(&gctr[g], 1);
        const int tgt = (s + 1) * 4;
        int cv;
        do {
            __builtin_amdgcn_s_sleep(1);
            cv = __builtin_amdgcn_readfirstlane(*(volatile int*)&gctr[g]);
        } while (cv < tgt);
    };

    auto STEP = [&](int s, f16x8 (&kc)[4], f16x8 (&kn)[4]) {
        const int j0  = (cbase + s) * 64;
        const int par = s & 1;
        unsigned char* pb = smem + g * 16384 + par * 8192;

        // issue V frag loads now; consumed after the sync (latency hidden)
        const int jblk0 = j0 >> 5;
        f16x8 vf[2][4];
#pragma unroll
        for (int jh = 0; jh < 2; ++jh)
#pragma unroll
            for (int cs = 0; cs < 4; ++cs)
                vf[jh][cs] = *reinterpret_cast<const f16x8*>(
                    vpc + (size_t)((jblk0 + jh) * 16 + cs) * 512);
        // prefetch next step's K
        const int jn = (s + 1 < nsteps) ? (j0 + 64) : cbase * 64;
        LOADK(kn, jn);

        // ---- QK^T swapped: D[j][i], col=i=irow, lane holds 16 j values ----
        f32x4 sv[4];
#pragma unroll
        for (int t = 0; t < 4; ++t)
            sv[t] = __builtin_amdgcn_mfma_f32_16x16x32_f16(kc[t], qfrag, zero4, 0, 0, 0);

        // ---- softmax (log2 domain): shuffle-free common path ----
        float pm = sv[0][0];
#pragma unroll
        for (int t = 0; t < 4; ++t)
#pragma unroll
            for (int r = 0; r < 4; ++r) pm = fmaxf(pm, sv[t][r]);
        float sc = 1.0f;
        int myresc = 0;
        if (__ballot(pm <= mrow + 8.0f) != ~0ull) {
            float pr = fmaxf(pm, __shfl_xor(pm, 16));
            pr = fmaxf(pr, __shfl_xor(pr, 32));
            const float mnew = fmaxf(mrow, pr);
            sc = fexp2(mrow - mnew);
            mrow = mnew;
            myresc = 1;
        }
        float rs = 0.f;
#pragma unroll
        for (int t = 0; t < 4; ++t)
#pragma unroll
            for (int r = 0; r < 4; ++r) { sv[t][r] = fexp2(sv[t][r] - mrow); rs += sv[t][r]; }
        lrow = lrow * sc + rs;

        // ---- P -> LDS (4x ds_write_b64, swizzled) + scale + flag ----
#pragma unroll
        for (int t = 0; t < 4; ++t) {
            u32x2 pw;
            pw[0] = __builtin_bit_cast(unsigned int,
                        __builtin_amdgcn_cvt_pkrtz(sv[t][0], sv[t][1]));
            pw[1] = __builtin_bit_cast(unsigned int,
                        __builtin_amdgcn_cvt_pkrtz(sv[t][2], sv[t][3]));
            const int lo = (irow * 128 + t * 32 + g4 * 8) ^ iswz;
            *reinterpret_cast<u32x2*>(pb + lo) = pw;
        }
        if (g4 == 0)   scales[(g * 2 + par) * 64 + irow] = sc;
        if (lane == 0) flags[(g * 2 + par) * 4 + ws] = myresc;

        GSYNC(s);   // group-local; other groups unconstrained

        // ---- rescale oacc if any row of the group rescaled ----
        const i32x4 fl = *reinterpret_cast<const i32x4*>(flags + (g * 2 + par) * 4);
        const int anyresc = __builtin_amdgcn_readfirstlane(fl[0] | fl[1] | fl[2] | fl[3]);
        if (anyresc) {
#pragma unroll
            for (int is = 0; is < 4; ++is) {
                const f32x4 sr = *reinterpret_cast<const f32x4*>(
                    scales + (g * 2 + par) * 64 + is * 16 + g4 * 4);
#pragma unroll
                for (int r = 0; r < 4; ++r)
#pragma unroll
                    for (int cs = 0; cs < 4; ++cs) oacc[is][cs][r] *= sr[r];
            }
        }

        // ---- PV: P A-frags from LDS, V B-frags in registers ----
        __builtin_amdgcn_s_setprio(1);
#pragma unroll
        for (int jh = 0; jh < 2; ++jh) {
#pragma unroll
            for (int is = 0; is < 4; ++is) {
                const int lo = ((is * 16 + m16) * 128 + jh * 64 + g4 * 16) ^ iswz;
                const f16x8 pf = *reinterpret_cast<const f16x8*>(pb + lo);
#pragma unroll
                for (int cs = 0; cs < 4; ++cs)
                    oacc[is][cs] = __builtin_amdgcn_mfma_f32_16x16x32_f16(
                        pf, vf[jh][cs], oacc[is][cs], 0, 0, 0);
            }
        }
        __builtin_amdgcn_s_setprio(0);
    };

    f16x8 kA[4], kB[4];
    LOADK(kA, cbase * 64);

#pragma unroll 1
    for (int s2 = 0; s2 < 11; ++s2) {
        const int s0 = 2 * s2, s1 = s0 + 1;
        if (s0 >= nsteps) break;
        STEP(s0, kA, kB);
        if (s1 >= nsteps) break;
        STEP(s1, kB, kA);
    }

    // ---- epilogue: reduce partial l across lanes, then 3-way flash combine ----
    lrow += __shfl_xor(lrow, 16);
    lrow += __shfl_xor(lrow, 32);
    if (g4 == 0) { mfin[g * 64 + irow] = mrow; lfin[g * 64 + irow] = lrow; }
    __syncthreads();

    if (tid < 192) {
        const int gg = tid >> 6, i = tid & 63;
        const float m0 = mfin[i], m1 = mfin[64 + i], m2 = mfin[128 + i];
        const float M  = fmaxf(fmaxf(m0, m1), m2);
        const float e0 = fexp2(m0 - M), e1 = fexp2(m1 - M), e2 = fexp2(m2 - M);
        const float den = lfin[i] * e0 + lfin[64 + i] * e1 + lfin[128 + i] * e2;
        wfac[gg * 64 + i] = ((gg == 0) ? e0 : (gg == 1) ? e1 : e2) / den;
    }
    __syncthreads();   // loop LDS dead; Ocomb aliases it from here

#pragma unroll
    for (int gg = 0; gg < 3; ++gg) {
        if (g == gg) {
#pragma unroll
            for (int is = 0; is < 4; ++is) {
                const f32x4 f = *reinterpret_cast<const f32x4*>(
                    wfac + g * 64 + is * 16 + g4 * 4);
#pragma unroll
                for (int cs = 0; cs < 4; ++cs)
#pragma unroll
                    for (int r = 0; r < 4; ++r) {
                        const int i = is * 16 + g4 * 4 + r;
                        const int c = ws * 64 + cs * 16 + m16;
                        if (gg == 0) Ocomb[i * 260 + c]  = oacc[is][cs][r] * f[r];
                        else         Ocomb[i * 260 + c] += oacc[is][cs][r] * f[r];
                    }
            }
        }
        __syncthreads();
    }

    const float gm = gamma[0];
#pragma unroll 1
    for (int q = tid; q < 4096; q += 768) {
        const int c  = q >> 4;
        const int ib = (q & 15) * 4;
        f32x4 o;
#pragma unroll
        for (int u = 0; u < 4; ++u) o[u] = Ocomb[(ib + u) * 260 + c];
        const size_t idx = ((size_t)(b * CD + c)) * ND + i0 + ib;
        const f32x4 xv = *reinterpret_cast<const f32x4*>(x + idx);
        f32x4 res;
#pragma unroll
        for (int u = 0; u < 4; ++u) res[u] = gm * o[u] + xv[u];
        *reinterpret_cast<f32x4*>(out + idx) = res;
    }
}

extern "C" void kernel_launch(void* const* d_in, const int* in_sizes, int n_in,
                              void* d_out, int out_size, void* d_ws, size_t ws_size,
                              hipStream_t stream) {
    const float* x     = (const float*)d_in[0];
    const float* wq    = (const float*)d_in[1];
    const float* bq    = (const float*)d_in[2];
    const float* wk    = (const float*)d_in[3];
    const float* bk    = (const float*)d_in[4];
    const float* wv    = (const float*)d_in[5];
    const float* bv    = (const float*)d_in[6];
    const float* gamma = (const float*)d_in[7];

    unsigned short* Qt = (unsigned short*)d_ws;               // 1MB (scaled by log2e)
    unsigned short* Kt = Qt + (size_t)NB * ND * CQ;           // 1MB
    unsigned short* Vp = Kt + (size_t)NB * ND * CQ;           // 8MB packed frags
    unsigned short* Wh = Vp + (size_t)NB * CD * ND;           // 160KB
    float* out = (float*)d_out;

    wcvt_kernel<<<dim3(80),      dim3(256), 0, stream>>>(wq, wk, wv, Wh);
    proj_kernel<<<dim3(NB * 64), dim3(320), 0, stream>>>(x, Wh, bq, bk, bv, Qt, Kt, Vp);
    attn_kernel<<<dim3(NB * 64), dim3(768), 0, stream>>>(Qt, Kt, Vp, x, gamma, out);
}